// Round 3
// baseline (278.851 us; speedup 1.0000x reference)
//
#include <hip/hip_runtime.h>

#define NN 50000   // nodes
#define NE 800000  // edges
#define DD 128     // feature dim
#define NPAD 50176 // 1024 * 49 (padded node count for the single-block scan)

// ---------------------------------------------------------------------------
// ws layout: cnt[NPAD] int | pos[NPAD] int | csr[NE] int | g[NN*DD] float
// ---------------------------------------------------------------------------

// 1) in-degree histogram
__global__ __launch_bounds__(256) void k_hist(const int* __restrict__ dst,
                                              int* __restrict__ cnt) {
  int e = blockIdx.x * 256 + threadIdx.x;
  if (e < NE) atomicAdd(&cnt[dst[e]], 1);
}

// 2) single-block exclusive scan of cnt[NPAD] -> pos (1024 thr x 49 elems)
__global__ __launch_bounds__(1024) void k_scan1(const int* __restrict__ cnt,
                                                int* __restrict__ pos) {
  __shared__ int sh[1024];
  int t = threadIdx.x;
  int base = t * 49;
  int ssum = 0;
  for (int i = 0; i < 49; ++i) ssum += cnt[base + i];
  sh[t] = ssum;
  __syncthreads();
  for (int o = 1; o < 1024; o <<= 1) {
    int x = (t >= o) ? sh[t - o] : 0;
    __syncthreads();
    sh[t] += x;
    __syncthreads();
  }
  int run = sh[t] - ssum;  // exclusive base of this thread's segment
  for (int i = 0; i < 49; ++i) {
    int v = cnt[base + i];
    pos[base + i] = run;
    run += v;
  }
}

// 3) fill CSR: csr[pos[dst]++] = src; afterwards pos[n] == end offset
__global__ __launch_bounds__(256) void k_fill(const int* __restrict__ src,
                                              const int* __restrict__ dst,
                                              int* __restrict__ pos,
                                              int* __restrict__ csr) {
  int e = blockIdx.x * 256 + threadIdx.x;
  if (e < NE) {
    int d = dst[e];
    int p = atomicAdd(&pos[d], 1);
    csr[p] = src[e];
  }
}

// 4) dense transform g = feature @ W^T  (mean commutes with the linear map)
// 256 rows x 128 cols per block, 256 threads, 16x8 per-thread tile.
// LDS demand 0.375 B/FLOP < 128 B/cyc supply -> VALU-bound, floor ~10.4us.
#define FMA8(R, H)                                          \
  {                                                         \
    acc[R][0] += (H)*w0.x; acc[R][1] += (H)*w0.y;           \
    acc[R][2] += (H)*w0.z; acc[R][3] += (H)*w0.w;           \
    acc[R][4] += (H)*w1.x; acc[R][5] += (H)*w1.y;           \
    acc[R][6] += (H)*w1.z; acc[R][7] += (H)*w1.w;           \
  }

__global__ __launch_bounds__(256) void k_gemmT(const float* __restrict__ feat,
                                               const float* __restrict__ W,
                                               float* __restrict__ g) {
  __shared__ float fs[32][260];  // [k][row], stride 260 (16B-aligned, bank-rot 4)
  __shared__ float ws[32][132];  // [k][col], stride 132
  int tid = threadIdx.x;
  int row0 = blockIdx.x * 256;
  int tc = tid & 15;   // cols 8*tc .. 8*tc+7
  int tr = tid >> 4;   // rows 16*tr .. 16*tr+15
  float acc[16][8] = {};

  for (int kc = 0; kc < 4; ++kc) {  // K chunks of 32
    if (kc) __syncthreads();
    // stage feature chunk: 256 rows x 8 float4
    for (int i = 0; i < 8; ++i) {
      int fidx = tid + (i << 8);
      int r = fidx >> 3;
      int q = fidx & 7;
      int grow = row0 + r;
      float4 v = make_float4(0.f, 0.f, 0.f, 0.f);
      if (grow < NN) v = ((const float4*)feat)[grow * 32 + kc * 8 + q];
      int k = q << 2;
      fs[k + 0][r] = v.x;
      fs[k + 1][r] = v.y;
      fs[k + 2][r] = v.z;
      fs[k + 3][r] = v.w;
    }
    // stage W chunk: 128 cols x 8 float4
    for (int i = 0; i < 4; ++i) {
      int fidx = tid + (i << 8);
      int c = fidx >> 3;
      int q = fidx & 7;
      float4 v = ((const float4*)W)[c * 32 + kc * 8 + q];
      int k = q << 2;
      ws[k + 0][c] = v.x;
      ws[k + 1][c] = v.y;
      ws[k + 2][c] = v.z;
      ws[k + 3][c] = v.w;
    }
    __syncthreads();

#pragma unroll 8
    for (int k = 0; k < 32; ++k) {
      float4 w0 = *(const float4*)&ws[k][tc * 8];
      float4 w1 = *(const float4*)&ws[k][tc * 8 + 4];
      float4 h0 = *(const float4*)&fs[k][tr * 16];
      float4 h1 = *(const float4*)&fs[k][tr * 16 + 4];
      float4 h2 = *(const float4*)&fs[k][tr * 16 + 8];
      float4 h3 = *(const float4*)&fs[k][tr * 16 + 12];
      FMA8(0, h0.x) FMA8(1, h0.y) FMA8(2, h0.z) FMA8(3, h0.w)
      FMA8(4, h1.x) FMA8(5, h1.y) FMA8(6, h1.z) FMA8(7, h1.w)
      FMA8(8, h2.x) FMA8(9, h2.y) FMA8(10, h2.z) FMA8(11, h2.w)
      FMA8(12, h3.x) FMA8(13, h3.y) FMA8(14, h3.z) FMA8(15, h3.w)
    }
  }

#pragma unroll
  for (int r = 0; r < 16; ++r) {
    int grow = row0 + tr * 16 + r;
    if (grow < NN) {
      float4 o0, o1;
      o0.x = acc[r][0]; o0.y = acc[r][1]; o0.z = acc[r][2]; o0.w = acc[r][3];
      o1.x = acc[r][4]; o1.y = acc[r][5]; o1.z = acc[r][6]; o1.w = acc[r][7];
      float4* gp = (float4*)(g + (long long)grow * DD) + tc * 2;
      gp[0] = o0;
      gp[1] = o1;
    }
  }
}

// 5) gather-mean over g + bias + relu -> out. One wave per node.
// Paired-edge float4: lanes 0-31 = edge j, lanes 32-63 = edge j+1 (16B/lane).
__global__ __launch_bounds__(256) void k_gmean(const float* __restrict__ g,
                                               const int* __restrict__ csr,
                                               const int* __restrict__ pos,
                                               const int* __restrict__ cnt,
                                               const float* __restrict__ bias,
                                               float* __restrict__ out) {
  int n = blockIdx.x * 4 + (threadIdx.x >> 6);  // 12500*4 == 50000
  int lane = threadIdx.x & 63;
  int half = lane >> 5;
  int l32 = lane & 31;
  int end = pos[n];
  int c = cnt[n];
  float4 a = make_float4(0.f, 0.f, 0.f, 0.f);
  for (int base = end - c; base < end; base += 64) {
    int m = end - base;
    if (m > 64) m = 64;
    int s = (base + lane < end) ? csr[base + lane] : 0;
    for (int j = 0; j < m; j += 8) {
#pragma unroll
      for (int u = 0; u < 4; ++u) {
        int j2 = j + 2 * u + half;
        int sj = __shfl(s, j2);
        if (j2 < m) {
          float4 v = ((const float4*)(g + (long long)sj * DD))[l32];
          a.x += v.x; a.y += v.y; a.z += v.z; a.w += v.w;
        }
      }
    }
  }
  // combine the two half-wave partial sums
  a.x += __shfl_xor(a.x, 32);
  a.y += __shfl_xor(a.y, 32);
  a.z += __shfl_xor(a.z, 32);
  a.w += __shfl_xor(a.w, 32);
  if (half == 0) {
    float inv = 1.0f / fmaxf((float)c, 1.0f);
    float4 b4 = ((const float4*)bias)[l32];
    float4 o;
    o.x = fmaxf(a.x * inv + b4.x, 0.f);
    o.y = fmaxf(a.y * inv + b4.y, 0.f);
    o.z = fmaxf(a.z * inv + b4.z, 0.f);
    o.w = fmaxf(a.w * inv + b4.w, 0.f);
    ((float4*)(out + (long long)n * DD))[l32] = o;
  }
}

// ---------------------------------------------------------------------------
// Fallback path (ws too small for g): round-2 validated kernels.
// gather feature -> sum in d_out, then in-place mean+GEMM+bias+relu.
// ---------------------------------------------------------------------------
__global__ __launch_bounds__(256) void k_gather_sum(const float* __restrict__ feat,
                                                    const int* __restrict__ csr,
                                                    const int* __restrict__ pos,
                                                    const int* __restrict__ cnt,
                                                    float* __restrict__ sum) {
  int n = blockIdx.x * 4 + (threadIdx.x >> 6);
  int lane = threadIdx.x & 63;
  int end = pos[n];
  int c = cnt[n];
  float ax = 0.f, ay = 0.f;
  for (int base = end - c; base < end; base += 64) {
    int m = end - base;
    if (m > 64) m = 64;
    int s = (base + lane < end) ? csr[base + lane] : 0;
    int j = 0;
    for (; j + 3 < m; j += 4) {
      int s0 = __shfl(s, j), s1 = __shfl(s, j + 1);
      int s2 = __shfl(s, j + 2), s3 = __shfl(s, j + 3);
      float2 v0 = ((const float2*)(feat + (long long)s0 * DD))[lane];
      float2 v1 = ((const float2*)(feat + (long long)s1 * DD))[lane];
      float2 v2 = ((const float2*)(feat + (long long)s2 * DD))[lane];
      float2 v3 = ((const float2*)(feat + (long long)s3 * DD))[lane];
      ax += (v0.x + v1.x) + (v2.x + v3.x);
      ay += (v0.y + v1.y) + (v2.y + v3.y);
    }
    for (; j < m; ++j) {
      int sj = __shfl(s, j);
      float2 v = ((const float2*)(feat + (long long)sj * DD))[lane];
      ax += v.x;
      ay += v.y;
    }
  }
  float2 o;
  o.x = ax;
  o.y = ay;
  ((float2*)(sum + (long long)n * DD))[lane] = o;
}

__global__ __launch_bounds__(256) void k_gemm_inplace(float* __restrict__ io,
                                                      const int* __restrict__ cnt,
                                                      const float* __restrict__ W,
                                                      const float* __restrict__ bias) {
  __shared__ float Wt[64][132];
  __shared__ __attribute__((aligned(16))) float hs[64][72];
  int tid = threadIdx.x;
  int row0 = blockIdx.x * 64;
  int tc = tid & 31;
  int tr = tid >> 5;
  float acc[8][4] = {};
  for (int p = 0; p < 2; ++p) {
    if (p) __syncthreads();
    for (int i = 0; i < 8; ++i) {
      int fidx = tid + (i << 8);
      int c = fidx >> 4;
      int kq = fidx & 15;
      float4 w = ((const float4*)W)[c * 32 + p * 16 + kq];
      int kk = kq << 2;
      Wt[kk + 0][c ^ (((kk + 0) & 31) << 2)] = w.x;
      Wt[kk + 1][c ^ (((kk + 1) & 31) << 2)] = w.y;
      Wt[kk + 2][c ^ (((kk + 2) & 31) << 2)] = w.z;
      Wt[kk + 3][c ^ (((kk + 3) & 31) << 2)] = w.w;
    }
    for (int i = 0; i < 4; ++i) {
      int fidx = tid + (i << 8);
      int r = fidx & 63;
      int kq = fidx >> 6;
      int grow = row0 + r;
      float4 v = make_float4(0.f, 0.f, 0.f, 0.f);
      if (grow < NN) {
        v = ((const float4*)io)[(long long)grow * 32 + p * 16 + kq];
        float inv = 1.0f / fmaxf((float)cnt[grow], 1.0f);
        v.x *= inv; v.y *= inv; v.z *= inv; v.w *= inv;
      }
      int kk = kq << 2;
      hs[kk + 0][r] = v.x;
      hs[kk + 1][r] = v.y;
      hs[kk + 2][r] = v.z;
      hs[kk + 3][r] = v.w;
    }
    __syncthreads();
#pragma unroll 4
    for (int kk = 0; kk < 64; ++kk) {
      float4 w4 = *(const float4*)&Wt[kk][(tc << 2) ^ ((kk & 31) << 2)];
      float4 h0 = *(const float4*)&hs[kk][tr << 3];
      float4 h1 = *(const float4*)&hs[kk][(tr << 3) + 4];
      acc[0][0] += h0.x * w4.x; acc[0][1] += h0.x * w4.y; acc[0][2] += h0.x * w4.z; acc[0][3] += h0.x * w4.w;
      acc[1][0] += h0.y * w4.x; acc[1][1] += h0.y * w4.y; acc[1][2] += h0.y * w4.z; acc[1][3] += h0.y * w4.w;
      acc[2][0] += h0.z * w4.x; acc[2][1] += h0.z * w4.y; acc[2][2] += h0.z * w4.z; acc[2][3] += h0.z * w4.w;
      acc[3][0] += h0.w * w4.x; acc[3][1] += h0.w * w4.y; acc[3][2] += h0.w * w4.z; acc[3][3] += h0.w * w4.w;
      acc[4][0] += h1.x * w4.x; acc[4][1] += h1.x * w4.y; acc[4][2] += h1.x * w4.z; acc[4][3] += h1.x * w4.w;
      acc[5][0] += h1.y * w4.x; acc[5][1] += h1.y * w4.y; acc[5][2] += h1.y * w4.z; acc[5][3] += h1.y * w4.w;
      acc[6][0] += h1.z * w4.x; acc[6][1] += h1.z * w4.y; acc[6][2] += h1.z * w4.z; acc[6][3] += h1.z * w4.w;
      acc[7][0] += h1.w * w4.x; acc[7][1] += h1.w * w4.y; acc[7][2] += h1.w * w4.z; acc[7][3] += h1.w * w4.w;
    }
  }
  float4 b4 = ((const float4*)bias)[tc];
#pragma unroll
  for (int r = 0; r < 8; ++r) {
    int row = row0 + (tr << 3) + r;
    if (row < NN) {
      float4 o;
      o.x = fmaxf(acc[r][0] + b4.x, 0.f);
      o.y = fmaxf(acc[r][1] + b4.y, 0.f);
      o.z = fmaxf(acc[r][2] + b4.z, 0.f);
      o.w = fmaxf(acc[r][3] + b4.w, 0.f);
      ((float4*)(io + (long long)row * DD))[tc] = o;
    }
  }
}

extern "C" void kernel_launch(void* const* d_in, const int* in_sizes, int n_in,
                              void* d_out, int out_size, void* d_ws, size_t ws_size,
                              hipStream_t stream) {
  const float* feature = (const float*)d_in[0];
  const int*   src     = (const int*)d_in[1];
  const int*   dst     = (const int*)d_in[2];
  const float* W       = (const float*)d_in[3];
  const float* bias    = (const float*)d_in[4];
  float* out = (float*)d_out;

  int* cnt = (int*)d_ws;
  int* pos = cnt + NPAD;
  int* csr = pos + NPAD;
  float* g = (float*)(csr + NE);  // byte offset 3,601,408 (16B aligned)

  size_t need_csr = (size_t)(2 * NPAD + NE) * sizeof(int);
  size_t need_g = need_csr + (size_t)NN * DD * sizeof(float);
  int nblk_e = (NE + 255) / 256;  // 3125

  hipMemsetAsync(cnt, 0, NPAD * sizeof(int), stream);
  hipLaunchKernelGGL(k_hist, dim3(nblk_e), dim3(256), 0, stream, dst, cnt);
  hipLaunchKernelGGL(k_scan1, dim3(1), dim3(1024), 0, stream, cnt, pos);
  hipLaunchKernelGGL(k_fill, dim3(nblk_e), dim3(256), 0, stream, src, dst, pos, csr);

  if (ws_size >= need_g) {
    // transform-first: g = feature @ W^T, then gather-mean+bias+relu
    hipLaunchKernelGGL(k_gemmT, dim3((NN + 255) / 256), dim3(256), 0, stream,
                       feature, W, g);
    hipLaunchKernelGGL(k_gmean, dim3(NN / 4), dim3(256), 0, stream,
                       g, csr, pos, cnt, bias, out);
  } else {
    // fallback: aggregate-first (round-2 validated path)
    hipLaunchKernelGGL(k_gather_sum, dim3(NN / 4), dim3(256), 0, stream,
                       feature, csr, pos, cnt, out);
    hipLaunchKernelGGL(k_gemm_inplace, dim3((NN + 63) / 64), dim3(256), 0,
                       stream, out, cnt, W, bias);
  }
}

// Round 8
// 251.964 us; speedup vs baseline: 1.1067x; 1.1067x over previous
//
#include <hip/hip_runtime.h>

#define NN 50000   // nodes
#define NE 800000  // edges
#define DD 128     // feature dim
#define NPAD 50176 // 49 * 1024
#define NSB 49     // scan blocks
#define GB 784     // gemm blocks in fused K1 (392 row-groups x 2 col-groups)
#define HB 782     // hist blocks (100000 threads / 128)

// ws layout (ints): cnt[NPAD] | pos[NPAD] | bsum[64] | csr[NE] | g[NN*DD] f32

#define ACC4(A, V) { A.x += V.x; A.y += V.y; A.z += V.z; A.w += V.w; }

// 49-element exclusive prefix of bsum into sbase[] (wave 0 does a shfl scan)
#define BSUM_PREFIX(bsum, sbase)                                   \
  {                                                                \
    int tt = threadIdx.x;                                          \
    if (tt < 64) {                                                 \
      int b = (tt < NSB) ? bsum[tt] : 0;                           \
      int z = b;                                                   \
      _Pragma("unroll") for (int o = 1; o < 64; o <<= 1) {         \
        int w_ = __shfl_up(z, o);                                  \
        if (tt >= o) z += w_;                                      \
      }                                                            \
      sbase[tt] = z - b;                                           \
    }                                                              \
    __syncthreads();                                               \
  }

// ---------------------------------------------------------------------------
// K1: fused dense transform g = feature @ W^T  (blocks [0,GB))  in parallel
//     with in-degree histogram (blocks [GB, GB+HB)).
// GEMM: 128 rows x 64 cols per block, 128 threads, 8x8 per-thread tile.
// ---------------------------------------------------------------------------
__global__ __launch_bounds__(128) void k_gemm_hist(
    const float* __restrict__ feat, const float* __restrict__ W,
    float* __restrict__ g, const int* __restrict__ dst, int* __restrict__ cnt) {
  __shared__ float fs[32][132];  // [k][row]   528B rows (16B aligned)
  __shared__ float ws[32][68];   // [k][swz(col)] 272B rows
  int tid = threadIdx.x;
  int bid = blockIdx.x;

  if (bid >= GB) {  // ---- histogram path: 8 edges per thread via 2x int4
    int idx = (bid - GB) * 128 + tid;
    if (idx < NE / 8) {
      const int4* d4 = (const int4*)dst;
      int4 a = d4[idx * 2];
      int4 b = d4[idx * 2 + 1];
      atomicAdd(&cnt[a.x], 1); atomicAdd(&cnt[a.y], 1);
      atomicAdd(&cnt[a.z], 1); atomicAdd(&cnt[a.w], 1);
      atomicAdd(&cnt[b.x], 1); atomicAdd(&cnt[b.y], 1);
      atomicAdd(&cnt[b.z], 1); atomicAdd(&cnt[b.w], 1);
    }
    return;
  }

  // ---- GEMM path
  int row0 = (bid >> 1) * 128;
  int col0 = (bid & 1) * 64;
  int tc = tid & 7;    // col group: cols col0 + 8*tc .. +7
  int trb = tid >> 3;  // row group: rows row0 + 8*trb .. +7
  int wbase = tc * 8 + ((tc >> 2) << 2);  // swizzled, conflict-free reads
  float acc[8][8] = {};

  for (int kc = 0; kc < 4; ++kc) {
    if (kc) __syncthreads();
    // stage feature chunk: 128 rows x 8 float4 (k-major in LDS)
    for (int i = 0; i < 8; ++i) {
      int fidx = tid + (i << 7);
      int r = fidx >> 3, q = fidx & 7;
      int grow = row0 + r;
      float4 v = make_float4(0.f, 0.f, 0.f, 0.f);
      if (grow < NN) v = ((const float4*)feat)[grow * 32 + kc * 8 + q];
      int k = q << 2;
      fs[k][r] = v.x; fs[k + 1][r] = v.y; fs[k + 2][r] = v.z; fs[k + 3][r] = v.w;
    }
    // stage W chunk: 64 cols x 8 float4, swizzled column placement
    for (int i = 0; i < 4; ++i) {
      int fidx = tid + (i << 7);
      int c = fidx >> 3, q = fidx & 7;
      float4 v = ((const float4*)W)[(col0 + c) * 32 + kc * 8 + q];
      int sc = c + ((c >> 5) << 2);
      int k = q << 2;
      ws[k][sc] = v.x; ws[k + 1][sc] = v.y; ws[k + 2][sc] = v.z; ws[k + 3][sc] = v.w;
    }
    __syncthreads();

#define FM8(R, H)                                                       \
    { acc[R][0] += (H)*w0.x; acc[R][1] += (H)*w0.y;                     \
      acc[R][2] += (H)*w0.z; acc[R][3] += (H)*w0.w;                     \
      acc[R][4] += (H)*w1.x; acc[R][5] += (H)*w1.y;                     \
      acc[R][6] += (H)*w1.z; acc[R][7] += (H)*w1.w; }

#pragma unroll 8
    for (int k = 0; k < 32; ++k) {
      float4 w0 = *(const float4*)&ws[k][wbase];
      float4 w1 = *(const float4*)&ws[k][wbase + 4];
      float4 h0 = *(const float4*)&fs[k][trb * 8];
      float4 h1 = *(const float4*)&fs[k][trb * 8 + 4];
      FM8(0, h0.x) FM8(1, h0.y) FM8(2, h0.z) FM8(3, h0.w)
      FM8(4, h1.x) FM8(5, h1.y) FM8(6, h1.z) FM8(7, h1.w)
    }
  }

#pragma unroll
  for (int r = 0; r < 8; ++r) {
    int grow = row0 + trb * 8 + r;
    if (grow < NN) {
      float4 o0, o1;
      o0.x = acc[r][0]; o0.y = acc[r][1]; o0.z = acc[r][2]; o0.w = acc[r][3];
      o1.x = acc[r][4]; o1.y = acc[r][5]; o1.z = acc[r][6]; o1.w = acc[r][7];
      float4* gp = (float4*)(g + (size_t)grow * DD + col0) + tc * 2;
      gp[0] = o0;
      gp[1] = o1;
    }
  }
}

// ---------------------------------------------------------------------------
// K2: coalesced block-local exclusive scan (49 blocks x 1024 thr), bsum out.
// ---------------------------------------------------------------------------
__global__ __launch_bounds__(1024) void k_scan(const int* __restrict__ cnt,
                                               int* __restrict__ pos,
                                               int* __restrict__ bsum) {
  __shared__ int wsum[16];
  int t = threadIdx.x;
  int gidx = blockIdx.x * 1024 + t;
  int v = cnt[gidx];
  int x = v;
#pragma unroll
  for (int o = 1; o < 64; o <<= 1) {
    int y = __shfl_up(x, o);
    if ((t & 63) >= o) x += y;
  }
  if ((t & 63) == 63) wsum[t >> 6] = x;
  __syncthreads();
  if (t < 64) {
    int y = (t < 16) ? wsum[t] : 0;
    int z = y;
#pragma unroll
    for (int o = 1; o < 16; o <<= 1) {
      int w = __shfl_up(z, o);
      if (t >= o) z += w;
    }
    if (t < 16) wsum[t] = z - y;  // exclusive wave base
  }
  __syncthreads();
  pos[gidx] = wsum[t >> 6] + x - v;  // block-local exclusive prefix
  if (t == 1023) bsum[blockIdx.x] = wsum[15] + x;
}

// ---------------------------------------------------------------------------
// K3: fill CSR. csr[sbase[d>>10] + pos[d]++] = src. 4 edges/thread via int4.
// ---------------------------------------------------------------------------
__global__ __launch_bounds__(256) void k_fill(const int* __restrict__ src,
                                              const int* __restrict__ dst,
                                              int* __restrict__ pos,
                                              int* __restrict__ csr,
                                              const int* __restrict__ bsum) {
  __shared__ int sbase[64];
  BSUM_PREFIX(bsum, sbase)
  int idx = blockIdx.x * 256 + threadIdx.x;
  if (idx < NE / 4) {
    int4 d = ((const int4*)dst)[idx];
    int4 s = ((const int4*)src)[idx];
    int p;
    p = atomicAdd(&pos[d.x], 1); csr[sbase[d.x >> 10] + p] = s.x;
    p = atomicAdd(&pos[d.y], 1); csr[sbase[d.y >> 10] + p] = s.y;
    p = atomicAdd(&pos[d.z], 1); csr[sbase[d.z >> 10] + p] = s.z;
    p = atomicAdd(&pos[d.w], 1); csr[sbase[d.w >> 10] + p] = s.w;
  }
}

// ---------------------------------------------------------------------------
// K4: gather-mean over g + bias + relu. One node per 32-lane half-wave
// (float4 x 32 lanes = full 128-col row). Unroll-8 unguarded load groups.
// ---------------------------------------------------------------------------
__global__ __launch_bounds__(256) void k_gmean(const float* __restrict__ g,
                                               const int* __restrict__ csr,
                                               const int* __restrict__ pos,
                                               const int* __restrict__ cnt,
                                               const int* __restrict__ bsum,
                                               const float* __restrict__ bias,
                                               float* __restrict__ out) {
  __shared__ int sbase[64];
  BSUM_PREFIX(bsum, sbase)
  int tid = threadIdx.x;
  int hw = tid >> 5, l32 = tid & 31;
  int n = blockIdx.x * 8 + hw;  // 6250*8 == 50000 exact
  int c = cnt[n];
  int endg = sbase[n >> 10] + pos[n];
  int start = endg - c;
  float4 a0 = make_float4(0.f, 0.f, 0.f, 0.f), a1 = a0, a2 = a0, a3 = a0;

  for (int base = start; base < endg; base += 32) {
    int m = endg - base;
    if (m > 32) m = 32;
    int s = (l32 < m) ? csr[base + l32] : 0;
    int j = 0;
    for (; j + 8 <= m; j += 8) {
      int s0 = __shfl(s, j + 0, 32), s1 = __shfl(s, j + 1, 32),
          s2 = __shfl(s, j + 2, 32), s3 = __shfl(s, j + 3, 32),
          s4 = __shfl(s, j + 4, 32), s5 = __shfl(s, j + 5, 32),
          s6 = __shfl(s, j + 6, 32), s7 = __shfl(s, j + 7, 32);
      float4 v0 = ((const float4*)(g + (size_t)s0 * DD))[l32];
      float4 v1 = ((const float4*)(g + (size_t)s1 * DD))[l32];
      float4 v2 = ((const float4*)(g + (size_t)s2 * DD))[l32];
      float4 v3 = ((const float4*)(g + (size_t)s3 * DD))[l32];
      float4 v4 = ((const float4*)(g + (size_t)s4 * DD))[l32];
      float4 v5 = ((const float4*)(g + (size_t)s5 * DD))[l32];
      float4 v6 = ((const float4*)(g + (size_t)s6 * DD))[l32];
      float4 v7 = ((const float4*)(g + (size_t)s7 * DD))[l32];
      ACC4(a0, v0) ACC4(a1, v1) ACC4(a2, v2) ACC4(a3, v3)
      ACC4(a0, v4) ACC4(a1, v5) ACC4(a2, v6) ACC4(a3, v7)
    }
    for (; j < m; ++j) {
      int sj = __shfl(s, j, 32);
      float4 v = ((const float4*)(g + (size_t)sj * DD))[l32];
      ACC4(a0, v)
    }
  }
  a0.x += a1.x + a2.x + a3.x;
  a0.y += a1.y + a2.y + a3.y;
  a0.z += a1.z + a2.z + a3.z;
  a0.w += a1.w + a2.w + a3.w;
  float inv = 1.0f / fmaxf((float)c, 1.0f);
  float4 b4 = ((const float4*)bias)[l32];
  float4 o;
  o.x = fmaxf(a0.x * inv + b4.x, 0.f);
  o.y = fmaxf(a0.y * inv + b4.y, 0.f);
  o.z = fmaxf(a0.z * inv + b4.z, 0.f);
  o.w = fmaxf(a0.w * inv + b4.w, 0.f);
  ((float4*)(out + (size_t)n * DD))[l32] = o;
}

// ---------------------------------------------------------------------------
// Fallback kernels (ws too small for g): gather raw feature sums, then
// in-place mean+GEMM+bias+relu (round-2/3 proven design).
// ---------------------------------------------------------------------------
__global__ __launch_bounds__(128) void k_hist(const int* __restrict__ dst,
                                              int* __restrict__ cnt) {
  int idx = blockIdx.x * 128 + threadIdx.x;
  if (idx < NE / 8) {
    const int4* d4 = (const int4*)dst;
    int4 a = d4[idx * 2];
    int4 b = d4[idx * 2 + 1];
    atomicAdd(&cnt[a.x], 1); atomicAdd(&cnt[a.y], 1);
    atomicAdd(&cnt[a.z], 1); atomicAdd(&cnt[a.w], 1);
    atomicAdd(&cnt[b.x], 1); atomicAdd(&cnt[b.y], 1);
    atomicAdd(&cnt[b.z], 1); atomicAdd(&cnt[b.w], 1);
  }
}

__global__ __launch_bounds__(256) void k_gsum(const float* __restrict__ feat,
                                              const int* __restrict__ csr,
                                              const int* __restrict__ pos,
                                              const int* __restrict__ cnt,
                                              const int* __restrict__ bsum,
                                              float* __restrict__ out) {
  __shared__ int sbase[64];
  BSUM_PREFIX(bsum, sbase)
  int tid = threadIdx.x;
  int hw = tid >> 5, l32 = tid & 31;
  int n = blockIdx.x * 8 + hw;
  int c = cnt[n];
  int endg = sbase[n >> 10] + pos[n];
  int start = endg - c;
  float4 a0 = make_float4(0.f, 0.f, 0.f, 0.f), a1 = a0;
  for (int base = start; base < endg; base += 32) {
    int m = endg - base;
    if (m > 32) m = 32;
    int s = (l32 < m) ? csr[base + l32] : 0;
    for (int j = 0; j < m; ++j) {
      int sj = __shfl(s, j, 32);
      float4 v = ((const float4*)(feat + (size_t)sj * DD))[l32];
      if (j & 1) { ACC4(a1, v) } else { ACC4(a0, v) }
    }
  }
  a0.x += a1.x; a0.y += a1.y; a0.z += a1.z; a0.w += a1.w;
  ((float4*)(out + (size_t)n * DD))[l32] = a0;
}

__global__ __launch_bounds__(256) void k_gemm_inplace(float* __restrict__ io,
                                                      const int* __restrict__ cnt,
                                                      const float* __restrict__ W,
                                                      const float* __restrict__ bias) {
  __shared__ float Wt[64][132];
  __shared__ __attribute__((aligned(16))) float hs[64][72];
  int tid = threadIdx.x;
  int row0 = blockIdx.x * 64;
  int tc = tid & 31;
  int tr = tid >> 5;
  float acc[8][4] = {};
  for (int p = 0; p < 2; ++p) {
    if (p) __syncthreads();
    for (int i = 0; i < 8; ++i) {
      int fidx = tid + (i << 8);
      int c = fidx >> 4;
      int kq = fidx & 15;
      float4 w = ((const float4*)W)[c * 32 + p * 16 + kq];
      int kk = kq << 2;
      Wt[kk + 0][c ^ (((kk + 0) & 31) << 2)] = w.x;
      Wt[kk + 1][c ^ (((kk + 1) & 31) << 2)] = w.y;
      Wt[kk + 2][c ^ (((kk + 2) & 31) << 2)] = w.z;
      Wt[kk + 3][c ^ (((kk + 3) & 31) << 2)] = w.w;
    }
    for (int i = 0; i < 4; ++i) {
      int fidx = tid + (i << 8);
      int r = fidx & 63;
      int kq = fidx >> 6;
      int grow = row0 + r;
      float4 v = make_float4(0.f, 0.f, 0.f, 0.f);
      if (grow < NN) {
        v = ((const float4*)io)[(size_t)grow * 32 + p * 16 + kq];
        float inv = 1.0f / fmaxf((float)cnt[grow], 1.0f);
        v.x *= inv; v.y *= inv; v.z *= inv; v.w *= inv;
      }
      int kk = kq << 2;
      hs[kk + 0][r] = v.x;
      hs[kk + 1][r] = v.y;
      hs[kk + 2][r] = v.z;
      hs[kk + 3][r] = v.w;
    }
    __syncthreads();
#pragma unroll 4
    for (int kk = 0; kk < 64; ++kk) {
      float4 w4 = *(const float4*)&Wt[kk][(tc << 2) ^ ((kk & 31) << 2)];
      float4 h0 = *(const float4*)&hs[kk][tr << 3];
      float4 h1 = *(const float4*)&hs[kk][(tr << 3) + 4];
      acc[0][0] += h0.x * w4.x; acc[0][1] += h0.x * w4.y; acc[0][2] += h0.x * w4.z; acc[0][3] += h0.x * w4.w;
      acc[1][0] += h0.y * w4.x; acc[1][1] += h0.y * w4.y; acc[1][2] += h0.y * w4.z; acc[1][3] += h0.y * w4.w;
      acc[2][0] += h0.z * w4.x; acc[2][1] += h0.z * w4.y; acc[2][2] += h0.z * w4.z; acc[2][3] += h0.z * w4.w;
      acc[3][0] += h0.w * w4.x; acc[3][1] += h0.w * w4.y; acc[3][2] += h0.w * w4.z; acc[3][3] += h0.w * w4.w;
      acc[4][0] += h1.x * w4.x; acc[4][1] += h1.x * w4.y; acc[4][2] += h1.x * w4.z; acc[4][3] += h1.x * w4.w;
      acc[5][0] += h1.y * w4.x; acc[5][1] += h1.y * w4.y; acc[5][2] += h1.y * w4.z; acc[5][3] += h1.y * w4.w;
      acc[6][0] += h1.z * w4.x; acc[6][1] += h1.z * w4.y; acc[6][2] += h1.z * w4.z; acc[6][3] += h1.z * w4.w;
      acc[7][0] += h1.w * w4.x; acc[7][1] += h1.w * w4.y; acc[7][2] += h1.w * w4.z; acc[7][3] += h1.w * w4.w;
    }
  }
  float4 b4 = ((const float4*)bias)[tc];
#pragma unroll
  for (int r = 0; r < 8; ++r) {
    int row = row0 + (tr << 3) + r;
    if (row < NN) {
      float4 o;
      o.x = fmaxf(acc[r][0] + b4.x, 0.f);
      o.y = fmaxf(acc[r][1] + b4.y, 0.f);
      o.z = fmaxf(acc[r][2] + b4.z, 0.f);
      o.w = fmaxf(acc[r][3] + b4.w, 0.f);
      ((float4*)(io + (size_t)row * DD))[tc] = o;
    }
  }
}

extern "C" void kernel_launch(void* const* d_in, const int* in_sizes, int n_in,
                              void* d_out, int out_size, void* d_ws, size_t ws_size,
                              hipStream_t stream) {
  const float* feature = (const float*)d_in[0];
  const int*   src     = (const int*)d_in[1];
  const int*   dst     = (const int*)d_in[2];
  const float* W       = (const float*)d_in[3];
  const float* bias    = (const float*)d_in[4];
  float* out = (float*)d_out;

  int* cnt  = (int*)d_ws;
  int* pos  = cnt + NPAD;
  int* bsum = pos + NPAD;
  int* csr  = bsum + 64;
  float* g  = (float*)(csr + NE);  // 16B-aligned offset

  size_t need_main = (size_t)(2 * NPAD + 64 + NE) * 4 + (size_t)NN * DD * 4;

  hipMemsetAsync(cnt, 0, NPAD * sizeof(int), stream);

  if (ws_size >= need_main) {
    hipLaunchKernelGGL(k_gemm_hist, dim3(GB + HB), dim3(128), 0, stream,
                       feature, W, g, dst, cnt);
    hipLaunchKernelGGL(k_scan, dim3(NSB), dim3(1024), 0, stream, cnt, pos, bsum);
    hipLaunchKernelGGL(k_fill, dim3((NE / 4 + 255) / 256), dim3(256), 0, stream,
                       src, dst, pos, csr, bsum);
    hipLaunchKernelGGL(k_gmean, dim3(NN / 8), dim3(256), 0, stream,
                       g, csr, pos, cnt, bsum, bias, out);
  } else {
    hipLaunchKernelGGL(k_hist, dim3(HB), dim3(128), 0, stream, dst, cnt);
    hipLaunchKernelGGL(k_scan, dim3(NSB), dim3(1024), 0, stream, cnt, pos, bsum);
    hipLaunchKernelGGL(k_fill, dim3((NE / 4 + 255) / 256), dim3(256), 0, stream,
                       src, dst, pos, csr, bsum);
    hipLaunchKernelGGL(k_gsum, dim3(NN / 8), dim3(256), 0, stream,
                       feature, csr, pos, cnt, bsum, out);
    hipLaunchKernelGGL(k_gemm_inplace, dim3((NN + 63) / 64), dim3(256), 0,
                       stream, out, cnt, W, bias);
  }
}

// Round 10
// 240.313 us; speedup vs baseline: 1.1604x; 1.0485x over previous
//
#include <hip/hip_runtime.h>

#define NN 50000   // nodes
#define NE 800000  // edges
#define DD 128     // feature dim
#define NPAD 50176 // 49 * 1024
#define NSB 49     // scan blocks
#define WGB 512    // gemm-stream blocks (2048 waves)
#define HBW 391    // hist blocks appended to stream kernel (391*256 >= NE/8)
#define HB 782     // fallback hist grid (128 thr)

// ws layout (ints): cnt[NPAD] | pos[NPAD] | bsum[64] | csr[NE] | g[NN*DD] f32

#define ACC4(A, V) { A.x += V.x; A.y += V.y; A.z += V.z; A.w += V.w; }

// 49-element exclusive prefix of bsum into sbase[] (wave 0 does a shfl scan)
#define BSUM_PREFIX(bsum, sbase)                                   \
  {                                                                \
    int tt = threadIdx.x;                                          \
    if (tt < 64) {                                                 \
      int b = (tt < NSB) ? bsum[tt] : 0;                           \
      int z = b;                                                   \
      _Pragma("unroll") for (int o = 1; o < 64; o <<= 1) {         \
        int w_ = __shfl_up(z, o);                                  \
        if (tt >= o) z += w_;                                      \
      }                                                            \
      sbase[tt] = z - b;                                           \
    }                                                              \
    __syncthreads();                                               \
  }

// ---------------------------------------------------------------------------
// K1: streaming g = feature @ W^T (blocks [0,WGB)) + fused in-degree
//     histogram (blocks [WGB, WGB+HBW)).
// W staged ONCE in LDS (64KB, XOR-swizzled float4 rows); one barrier; then
// each wave independently streams 8-row groups: stage rows to its private
// hs slice (wave-synchronous, no barrier), k-loop of b128 reads + FMAs.
// Per lane: cols {lane, lane+64} x 8 rows. 80KB LDS -> 2 blocks/CU = 8 w/CU.
// ---------------------------------------------------------------------------
__global__ __launch_bounds__(256) void k_gemm_hist(
    const float* __restrict__ feat, const float* __restrict__ W,
    float* __restrict__ g, const int* __restrict__ dst, int* __restrict__ cnt) {
  __shared__ float4 Wc4[DD * 32];          // [c][kq^ (c&31)]  64KB
  __shared__ float hs[4][8][DD];           // per-wave 8-row buffer 16KB
  int tid = threadIdx.x;
  int bid = blockIdx.x;

  if (bid >= WGB) {  // ---- histogram path: 8 edges per thread via 2x int4
    int idx = (bid - WGB) * 256 + tid;
    if (idx < NE / 8) {
      const int4* d4 = (const int4*)dst;
      int4 a = d4[idx * 2];
      int4 b = d4[idx * 2 + 1];
      atomicAdd(&cnt[a.x], 1); atomicAdd(&cnt[a.y], 1);
      atomicAdd(&cnt[a.z], 1); atomicAdd(&cnt[a.w], 1);
      atomicAdd(&cnt[b.x], 1); atomicAdd(&cnt[b.y], 1);
      atomicAdd(&cnt[b.z], 1); atomicAdd(&cnt[b.w], 1);
    }
    return;
  }

  // ---- stage W (row-major W[c][k], c=out col): 4096 float4, 16/thread,
  //      swizzled column-quad placement: Wc4[c*32 + (kq ^ (c&31))]
  {
    const float4* W4 = (const float4*)W;
#pragma unroll
    for (int i = 0; i < 16; ++i) {
      int fidx = tid + (i << 8);
      int c = fidx >> 5, kq = fidx & 31;
      Wc4[c * 32 + (kq ^ (c & 31))] = W4[fidx];
    }
  }
  __syncthreads();

  int w = tid >> 6, lane = tid & 63;
  int s = lane & 31;  // swizzle key for both cols (lane and lane+64)
  const float2* feat2 = (const float2*)feat;

  for (int gid = bid * 4 + w; gid < NN / 8; gid += WGB * 4) {
    int r0 = gid * 8;
    // stage 8 rows, 8B/lane each: coalesced 512B loads, conflict-free writes
#pragma unroll
    for (int r = 0; r < 8; ++r) {
      float2 v = feat2[(size_t)(r0 + r) * 64 + lane];
      hs[w][r][lane * 2] = v.x;
      hs[w][r][lane * 2 + 1] = v.y;
    }
    float2 acc[8] = {};
#pragma unroll 2
    for (int kc = 0; kc < 32; ++kc) {
      float4 w0 = Wc4[lane * 32 + (kc ^ s)];
      float4 w1 = Wc4[(lane + 64) * 32 + (kc ^ s)];
#pragma unroll
      for (int r = 0; r < 8; ++r) {
        float4 h = *(const float4*)&hs[w][r][kc * 4];  // broadcast read
        acc[r].x += h.x * w0.x; acc[r].x += h.y * w0.y;
        acc[r].x += h.z * w0.z; acc[r].x += h.w * w0.w;
        acc[r].y += h.x * w1.x; acc[r].y += h.y * w1.y;
        acc[r].y += h.z * w1.z; acc[r].y += h.w * w1.w;
      }
    }
#pragma unroll
    for (int r = 0; r < 8; ++r) {
      g[(size_t)(r0 + r) * DD + lane] = acc[r].x;
      g[(size_t)(r0 + r) * DD + lane + 64] = acc[r].y;
    }
  }
}

// ---------------------------------------------------------------------------
// K2: coalesced block-local exclusive scan (49 blocks x 1024 thr), bsum out.
// ---------------------------------------------------------------------------
__global__ __launch_bounds__(1024) void k_scan(const int* __restrict__ cnt,
                                               int* __restrict__ pos,
                                               int* __restrict__ bsum) {
  __shared__ int wsum[16];
  int t = threadIdx.x;
  int gidx = blockIdx.x * 1024 + t;
  int v = cnt[gidx];
  int x = v;
#pragma unroll
  for (int o = 1; o < 64; o <<= 1) {
    int y = __shfl_up(x, o);
    if ((t & 63) >= o) x += y;
  }
  if ((t & 63) == 63) wsum[t >> 6] = x;
  __syncthreads();
  if (t < 64) {
    int y = (t < 16) ? wsum[t] : 0;
    int z = y;
#pragma unroll
    for (int o = 1; o < 16; o <<= 1) {
      int w = __shfl_up(z, o);
      if (t >= o) z += w;
    }
    if (t < 16) wsum[t] = z - y;  // exclusive wave base
  }
  __syncthreads();
  pos[gidx] = wsum[t >> 6] + x - v;  // block-local exclusive prefix
  if (t == 1023) bsum[blockIdx.x] = wsum[15] + x;
}

// ---------------------------------------------------------------------------
// K3: fill CSR. csr[sbase[d>>10] + pos[d]++] = src. 4 edges/thread via int4.
// ---------------------------------------------------------------------------
__global__ __launch_bounds__(256) void k_fill(const int* __restrict__ src,
                                              const int* __restrict__ dst,
                                              int* __restrict__ pos,
                                              int* __restrict__ csr,
                                              const int* __restrict__ bsum) {
  __shared__ int sbase[64];
  BSUM_PREFIX(bsum, sbase)
  int idx = blockIdx.x * 256 + threadIdx.x;
  if (idx < NE / 4) {
    int4 d = ((const int4*)dst)[idx];
    int4 s = ((const int4*)src)[idx];
    int p;
    p = atomicAdd(&pos[d.x], 1); csr[sbase[d.x >> 10] + p] = s.x;
    p = atomicAdd(&pos[d.y], 1); csr[sbase[d.y >> 10] + p] = s.y;
    p = atomicAdd(&pos[d.z], 1); csr[sbase[d.z >> 10] + p] = s.z;
    p = atomicAdd(&pos[d.w], 1); csr[sbase[d.w >> 10] + p] = s.w;
  }
}

// ---------------------------------------------------------------------------
// K4: gather-mean over g + bias + relu. One node per 32-lane half-wave
// (float4 x 32 lanes = full 128-col row). Unroll-8 unguarded load groups.
// ---------------------------------------------------------------------------
__global__ __launch_bounds__(256) void k_gmean(const float* __restrict__ g,
                                               const int* __restrict__ csr,
                                               const int* __restrict__ pos,
                                               const int* __restrict__ cnt,
                                               const int* __restrict__ bsum,
                                               const float* __restrict__ bias,
                                               float* __restrict__ out) {
  __shared__ int sbase[64];
  BSUM_PREFIX(bsum, sbase)
  int tid = threadIdx.x;
  int hw = tid >> 5, l32 = tid & 31;
  int n = blockIdx.x * 8 + hw;  // 6250*8 == 50000 exact
  int c = cnt[n];
  int endg = sbase[n >> 10] + pos[n];
  int start = endg - c;
  float4 a0 = make_float4(0.f, 0.f, 0.f, 0.f), a1 = a0, a2 = a0, a3 = a0;

  for (int base = start; base < endg; base += 32) {
    int m = endg - base;
    if (m > 32) m = 32;
    int s = (l32 < m) ? csr[base + l32] : 0;
    int j = 0;
    for (; j + 8 <= m; j += 8) {
      int s0 = __shfl(s, j + 0, 32), s1 = __shfl(s, j + 1, 32),
          s2 = __shfl(s, j + 2, 32), s3 = __shfl(s, j + 3, 32),
          s4 = __shfl(s, j + 4, 32), s5 = __shfl(s, j + 5, 32),
          s6 = __shfl(s, j + 6, 32), s7 = __shfl(s, j + 7, 32);
      float4 v0 = ((const float4*)(g + (size_t)s0 * DD))[l32];
      float4 v1 = ((const float4*)(g + (size_t)s1 * DD))[l32];
      float4 v2 = ((const float4*)(g + (size_t)s2 * DD))[l32];
      float4 v3 = ((const float4*)(g + (size_t)s3 * DD))[l32];
      float4 v4 = ((const float4*)(g + (size_t)s4 * DD))[l32];
      float4 v5 = ((const float4*)(g + (size_t)s5 * DD))[l32];
      float4 v6 = ((const float4*)(g + (size_t)s6 * DD))[l32];
      float4 v7 = ((const float4*)(g + (size_t)s7 * DD))[l32];
      ACC4(a0, v0) ACC4(a1, v1) ACC4(a2, v2) ACC4(a3, v3)
      ACC4(a0, v4) ACC4(a1, v5) ACC4(a2, v6) ACC4(a3, v7)
    }
    for (; j < m; ++j) {
      int sj = __shfl(s, j, 32);
      float4 v = ((const float4*)(g + (size_t)sj * DD))[l32];
      ACC4(a0, v)
    }
  }
  a0.x += a1.x + a2.x + a3.x;
  a0.y += a1.y + a2.y + a3.y;
  a0.z += a1.z + a2.z + a3.z;
  a0.w += a1.w + a2.w + a3.w;
  float inv = 1.0f / fmaxf((float)c, 1.0f);
  float4 b4 = ((const float4*)bias)[l32];
  float4 o;
  o.x = fmaxf(a0.x * inv + b4.x, 0.f);
  o.y = fmaxf(a0.y * inv + b4.y, 0.f);
  o.z = fmaxf(a0.z * inv + b4.z, 0.f);
  o.w = fmaxf(a0.w * inv + b4.w, 0.f);
  ((float4*)(out + (size_t)n * DD))[l32] = o;
}

// ---------------------------------------------------------------------------
// Fallback kernels (ws too small for g): gather raw feature sums, then
// in-place mean+GEMM+bias+relu (round-2/3 proven design).
// ---------------------------------------------------------------------------
__global__ __launch_bounds__(128) void k_hist(const int* __restrict__ dst,
                                              int* __restrict__ cnt) {
  int idx = blockIdx.x * 128 + threadIdx.x;
  if (idx < NE / 8) {
    const int4* d4 = (const int4*)dst;
    int4 a = d4[idx * 2];
    int4 b = d4[idx * 2 + 1];
    atomicAdd(&cnt[a.x], 1); atomicAdd(&cnt[a.y], 1);
    atomicAdd(&cnt[a.z], 1); atomicAdd(&cnt[a.w], 1);
    atomicAdd(&cnt[b.x], 1); atomicAdd(&cnt[b.y], 1);
    atomicAdd(&cnt[b.z], 1); atomicAdd(&cnt[b.w], 1);
  }
}

__global__ __launch_bounds__(256) void k_gsum(const float* __restrict__ feat,
                                              const int* __restrict__ csr,
                                              const int* __restrict__ pos,
                                              const int* __restrict__ cnt,
                                              const int* __restrict__ bsum,
                                              float* __restrict__ out) {
  __shared__ int sbase[64];
  BSUM_PREFIX(bsum, sbase)
  int tid = threadIdx.x;
  int hw = tid >> 5, l32 = tid & 31;
  int n = blockIdx.x * 8 + hw;
  int c = cnt[n];
  int endg = sbase[n >> 10] + pos[n];
  int start = endg - c;
  float4 a0 = make_float4(0.f, 0.f, 0.f, 0.f), a1 = a0;
  for (int base = start; base < endg; base += 32) {
    int m = endg - base;
    if (m > 32) m = 32;
    int s = (l32 < m) ? csr[base + l32] : 0;
    for (int j = 0; j < m; ++j) {
      int sj = __shfl(s, j, 32);
      float4 v = ((const float4*)(feat + (size_t)sj * DD))[l32];
      if (j & 1) { ACC4(a1, v) } else { ACC4(a0, v) }
    }
  }
  a0.x += a1.x; a0.y += a1.y; a0.z += a1.z; a0.w += a1.w;
  ((float4*)(out + (size_t)n * DD))[l32] = a0;
}

__global__ __launch_bounds__(256) void k_gemm_inplace(float* __restrict__ io,
                                                      const int* __restrict__ cnt,
                                                      const float* __restrict__ W,
                                                      const float* __restrict__ bias) {
  __shared__ float Wt[64][132];
  __shared__ __attribute__((aligned(16))) float hs[64][72];
  int tid = threadIdx.x;
  int row0 = blockIdx.x * 64;
  int tc = tid & 31;
  int tr = tid >> 5;
  float acc[8][4] = {};
  for (int p = 0; p < 2; ++p) {
    if (p) __syncthreads();
    for (int i = 0; i < 8; ++i) {
      int fidx = tid + (i << 8);
      int c = fidx >> 4;
      int kq = fidx & 15;
      float4 w = ((const float4*)W)[c * 32 + p * 16 + kq];
      int kk = kq << 2;
      Wt[kk + 0][c ^ (((kk + 0) & 31) << 2)] = w.x;
      Wt[kk + 1][c ^ (((kk + 1) & 31) << 2)] = w.y;
      Wt[kk + 2][c ^ (((kk + 2) & 31) << 2)] = w.z;
      Wt[kk + 3][c ^ (((kk + 3) & 31) << 2)] = w.w;
    }
    for (int i = 0; i < 4; ++i) {
      int fidx = tid + (i << 8);
      int r = fidx & 63;
      int kq = fidx >> 6;
      int grow = row0 + r;
      float4 v = make_float4(0.f, 0.f, 0.f, 0.f);
      if (grow < NN) {
        v = ((const float4*)io)[(size_t)grow * 32 + p * 16 + kq];
        float inv = 1.0f / fmaxf((float)cnt[grow], 1.0f);
        v.x *= inv; v.y *= inv; v.z *= inv; v.w *= inv;
      }
      int kk = kq << 2;
      hs[kk + 0][r] = v.x;
      hs[kk + 1][r] = v.y;
      hs[kk + 2][r] = v.z;
      hs[kk + 3][r] = v.w;
    }
    __syncthreads();
#pragma unroll 4
    for (int kk = 0; kk < 64; ++kk) {
      float4 w4 = *(const float4*)&Wt[kk][(tc << 2) ^ ((kk & 31) << 2)];
      float4 h0 = *(const float4*)&hs[kk][tr << 3];
      float4 h1 = *(const float4*)&hs[kk][(tr << 3) + 4];
      acc[0][0] += h0.x * w4.x; acc[0][1] += h0.x * w4.y; acc[0][2] += h0.x * w4.z; acc[0][3] += h0.x * w4.w;
      acc[1][0] += h0.y * w4.x; acc[1][1] += h0.y * w4.y; acc[1][2] += h0.y * w4.z; acc[1][3] += h0.y * w4.w;
      acc[2][0] += h0.z * w4.x; acc[2][1] += h0.z * w4.y; acc[2][2] += h0.z * w4.z; acc[2][3] += h0.z * w4.w;
      acc[3][0] += h0.w * w4.x; acc[3][1] += h0.w * w4.y; acc[3][2] += h0.w * w4.z; acc[3][3] += h0.w * w4.w;
      acc[4][0] += h1.x * w4.x; acc[4][1] += h1.x * w4.y; acc[4][2] += h1.x * w4.z; acc[4][3] += h1.x * w4.w;
      acc[5][0] += h1.y * w4.x; acc[5][1] += h1.y * w4.y; acc[5][2] += h1.y * w4.z; acc[5][3] += h1.y * w4.w;
      acc[6][0] += h1.z * w4.x; acc[6][1] += h1.z * w4.y; acc[6][2] += h1.z * w4.z; acc[6][3] += h1.z * w4.w;
      acc[7][0] += h1.w * w4.x; acc[7][1] += h1.w * w4.y; acc[7][2] += h1.w * w4.z; acc[7][3] += h1.w * w4.w;
    }
  }
  float4 b4 = ((const float4*)bias)[tc];
#pragma unroll
  for (int r = 0; r < 8; ++r) {
    int row = row0 + (tr << 3) + r;
    if (row < NN) {
      float4 o;
      o.x = fmaxf(acc[r][0] + b4.x, 0.f);
      o.y = fmaxf(acc[r][1] + b4.y, 0.f);
      o.z = fmaxf(acc[r][2] + b4.z, 0.f);
      o.w = fmaxf(acc[r][3] + b4.w, 0.f);
      ((float4*)(io + (size_t)row * DD))[tc] = o;
    }
  }
}

extern "C" void kernel_launch(void* const* d_in, const int* in_sizes, int n_in,
                              void* d_out, int out_size, void* d_ws, size_t ws_size,
                              hipStream_t stream) {
  const float* feature = (const float*)d_in[0];
  const int*   src     = (const int*)d_in[1];
  const int*   dst     = (const int*)d_in[2];
  const float* W       = (const float*)d_in[3];
  const float* bias    = (const float*)d_in[4];
  float* out = (float*)d_out;

  int* cnt  = (int*)d_ws;
  int* pos  = cnt + NPAD;
  int* bsum = pos + NPAD;
  int* csr  = bsum + 64;
  float* g  = (float*)(csr + NE);  // 16B-aligned offset

  size_t need_main = (size_t)(2 * NPAD + 64 + NE) * 4 + (size_t)NN * DD * 4;

  hipMemsetAsync(cnt, 0, NPAD * sizeof(int), stream);

  if (ws_size >= need_main) {
    hipLaunchKernelGGL(k_gemm_hist, dim3(WGB + HBW), dim3(256), 0, stream,
                       feature, W, g, dst, cnt);
    hipLaunchKernelGGL(k_scan, dim3(NSB), dim3(1024), 0, stream, cnt, pos, bsum);
    hipLaunchKernelGGL(k_fill, dim3((NE / 4 + 255) / 256), dim3(256), 0, stream,
                       src, dst, pos, csr, bsum);
    hipLaunchKernelGGL(k_gmean, dim3(NN / 8), dim3(256), 0, stream,
                       g, csr, pos, cnt, bsum, bias, out);
  } else {
    hipLaunchKernelGGL(k_hist, dim3(HB), dim3(128), 0, stream, dst, cnt);
    hipLaunchKernelGGL(k_scan, dim3(NSB), dim3(1024), 0, stream, cnt, pos, bsum);
    hipLaunchKernelGGL(k_fill, dim3((NE / 4 + 255) / 256), dim3(256), 0, stream,
                       src, dst, pos, csr, bsum);
    hipLaunchKernelGGL(k_gsum, dim3(NN / 8), dim3(256), 0, stream,
                       feature, csr, pos, cnt, bsum, out);
    hipLaunchKernelGGL(k_gemm_inplace, dim3((NN + 63) / 64), dim3(256), 0,
                       stream, out, cnt, W, bias);
  }
}